// Round 2
// 1981.189 us; speedup vs baseline: 1.0450x; 1.0450x over previous
//
#include <hip/hip_runtime.h>
#include <hip/hip_bf16.h>
#include <stdint.h>

// ============================================================================
// meta_optimizer (Stiefel retraction) via Cholesky-QR, fp16 MFMA + fp32 chol.
//
//   c  = |lr_b| * s
//   A  = M^T G                      (K1, fp16 MFMA, K=2304)
//   W  = I + c*0.5*(A + A^T)        (K1b, elementwise, fp16 out)
//   B  = M*W - c*(G+U)              (K2, fp16 MFMA, K=256, fused epilogue)
//   S  = B^T B                      (K3, fp16 MFMA, K=2304, fp32 out)
//   L  = chol(S);  Linv = L^-1      (S3, one 1024-thr WG/batch, fp32, NB=32)
//   out= Linv * B^T                 (K4, fp16 MFMA, K=256, fp32 out)
//
// All GEMMs are C[m][n] = sum_k Asrc[m][k]*Bsrc[n][k]  (= Asrc * Bsrc^T) with
// both sources stored [rows][k-contiguous] fp16, staged to LDS via
// global_load_lds(16B) with an XOR chunk swizzle (conflict-free ds_read_b128).
// ============================================================================

typedef _Float16 f16;
typedef _Float16 half4 __attribute__((ext_vector_type(4)));
typedef _Float16 half8 __attribute__((ext_vector_type(8)));
typedef float float4v __attribute__((ext_vector_type(4)));

#define AS1 __attribute__((address_space(1)))
#define AS3 __attribute__((address_space(3)))

__device__ __forceinline__ void gload_lds16(const f16* g, f16* l) {
  __builtin_amdgcn_global_load_lds((const AS1 void*)g, (AS3 void*)l, 16, 0, 0);
}

// ----------------------------------------------------------------------------
// prep: read M,G,U fp32; emit M16 [2304][256], Mt [256][2304], Gt [256][2304],
//       GU = c*(G+U) [2304][256]   (all fp16)
// grid (36, 2, 128), 256 thr. mode y==0: M -> M16+Mt. y==1: G,U -> Gt+GU.
// ----------------------------------------------------------------------------
__global__ __launch_bounds__(256) void prep_kernel(
    const float* __restrict__ M, const float* __restrict__ G,
    const float* __restrict__ U, const float* __restrict__ lr,
    const float* __restrict__ sl,
    f16* __restrict__ M16, f16* __restrict__ Mt,
    f16* __restrict__ Gt,  f16* __restrict__ GU)
{
  __shared__ f16 T[256 * 72];
  const int b = blockIdx.z, mode = blockIdx.y, r0 = blockIdx.x * 64;
  const int tid = threadIdx.x;
  const size_t bin = (size_t)b * 589824;
  const float* src = (mode ? G : M) + bin + (size_t)r0 * 256;
  const float* usrc = U + bin + (size_t)r0 * 256;
  const float cb = mode ? fabsf(lr[b]) * sl[0] : 0.f;

  for (int q = 0; q < 16; ++q) {
    int idx = q * 256 + tid;
    int rr = idx >> 6, c4 = (idx & 63) * 4;
    float4 v = *(const float4*)(src + (size_t)rr * 256 + c4);
    f16 h0 = (f16)v.x, h1 = (f16)v.y, h2 = (f16)v.z, h3 = (f16)v.w;
    T[(c4 + 0) * 72 + rr] = h0;
    T[(c4 + 1) * 72 + rr] = h1;
    T[(c4 + 2) * 72 + rr] = h2;
    T[(c4 + 3) * 72 + rr] = h3;
    if (mode == 0) {
      half4 hv; hv[0] = h0; hv[1] = h1; hv[2] = h2; hv[3] = h3;
      *(half4*)(M16 + bin + (size_t)(r0 + rr) * 256 + c4) = hv;
    } else {
      float4 u = *(const float4*)(usrc + (size_t)rr * 256 + c4);
      half4 gu;
      gu[0] = (f16)(cb * (v.x + u.x));
      gu[1] = (f16)(cb * (v.y + u.y));
      gu[2] = (f16)(cb * (v.z + u.z));
      gu[3] = (f16)(cb * (v.w + u.w));
      *(half4*)(GU + bin + (size_t)(r0 + rr) * 256 + c4) = gu;
    }
  }
  __syncthreads();
  f16* dst = (mode ? Gt : Mt) + bin;
  for (int q = 0; q < 8; ++q) {
    int idx = q * 256 + tid;
    int cc = idx >> 3, r8 = (idx & 7) * 8;
    half8 hv = *(const half8*)(T + cc * 72 + r8);
    *(half8*)(dst + (size_t)cc * 2304 + r0 + r8) = hv;
  }
}

// ----------------------------------------------------------------------------
// tranb: Bt [256][2304] = transpose of B16 [2304][256]. grid (36,1,128).
// ----------------------------------------------------------------------------
__global__ __launch_bounds__(256) void tranb_kernel(const f16* __restrict__ B,
                                                    f16* __restrict__ Bt)
{
  __shared__ f16 T[256 * 72];
  const int b = blockIdx.z, r0 = blockIdx.x * 64, tid = threadIdx.x;
  const size_t bin = (size_t)b * 589824;
  for (int q = 0; q < 8; ++q) {
    int idx = q * 256 + tid;
    int rr = idx >> 5, c8 = (idx & 31) * 8;
    half8 v = *(const half8*)(B + bin + (size_t)(r0 + rr) * 256 + c8);
#pragma unroll
    for (int i = 0; i < 8; ++i) T[(c8 + i) * 72 + rr] = v[i];
  }
  __syncthreads();
  for (int q = 0; q < 8; ++q) {
    int idx = q * 256 + tid;
    int cc = idx >> 3, r8 = (idx & 7) * 8;
    *(half8*)(Bt + bin + (size_t)cc * 2304 + r0 + r8) =
        *(const half8*)(T + cc * 72 + r8);
  }
}

// ----------------------------------------------------------------------------
// symw: W16 = I + 0.5*c*(A + A^T), fp16. grid (10,1,128): 10 = lower 4x4 tile
// pairs of 64x64 tiles; each WG emits tile (i,j) and (j,i).
// ----------------------------------------------------------------------------
__global__ __launch_bounds__(256) void symw_kernel(
    const float* __restrict__ A, const float* __restrict__ lr,
    const float* __restrict__ sl, f16* __restrict__ W)
{
  __shared__ float T1[64 * 65];
  __shared__ float T2[64 * 65];
  const int b = blockIdx.z, tid = threadIdx.x;
  int pr = blockIdx.x;
  int ti = 0;
  while ((ti + 1) * (ti + 2) / 2 <= pr) ++ti;
  int tj = pr - ti * (ti + 1) / 2;
  const int i0 = ti * 64, j0 = tj * 64;
  const float* Ab = A + (size_t)b * 65536;
  const float ch = 0.5f * fabsf(lr[b]) * sl[0];

  for (int q = 0; q < 4; ++q) {
    int idx = q * 256 + tid;
    int r = idx >> 4, c4 = (idx & 15) * 4;
    float4 v = *(const float4*)(Ab + (size_t)(i0 + r) * 256 + j0 + c4);
    T1[r * 65 + c4 + 0] = v.x; T1[r * 65 + c4 + 1] = v.y;
    T1[r * 65 + c4 + 2] = v.z; T1[r * 65 + c4 + 3] = v.w;
    if (ti != tj) {
      float4 w = *(const float4*)(Ab + (size_t)(j0 + r) * 256 + i0 + c4);
      T2[r * 65 + c4 + 0] = w.x; T2[r * 65 + c4 + 1] = w.y;
      T2[r * 65 + c4 + 2] = w.z; T2[r * 65 + c4 + 3] = w.w;
    }
  }
  __syncthreads();
  const float* T2p = (ti == tj) ? T1 : T2;
  f16* Wb = W + (size_t)b * 65536;
  for (int q = 0; q < 16; ++q) {
    int idx = q * 256 + tid;
    int r = idx >> 6, c = idx & 63;
    float val = ch * (T1[r * 65 + c] + T2p[c * 65 + r]);
    if (ti == tj && r == c) val += 1.f;
    Wb[(size_t)(i0 + r) * 256 + j0 + c] = (f16)val;
  }
  if (ti != tj) {
    for (int q = 0; q < 16; ++q) {
      int idx = q * 256 + tid;
      int r = idx >> 6, c = idx & 63;
      float val = ch * (T2[r * 65 + c] + T1[c * 65 + r]);
      Wb[(size_t)(j0 + r) * 256 + i0 + c] = (f16)val;
    }
  }
}

// ----------------------------------------------------------------------------
// GEMM: C[m][n] = sum_k Asrc[m][k] * Bsrc[n][k].  128x128 tile, BK=64,
// 256 thr (4 waves 2x2, each wave 64x64 = 4x4 mfma 16x16x32 f16).
// EPI 0: fp32 store to Cf.  EPI 1: fp16 store of (acc - GU) to C16.
// ----------------------------------------------------------------------------
template <int EPI>
__global__ __launch_bounds__(256) void gemm_kernel(
    const f16* __restrict__ Abase, long sA, int lda,
    const f16* __restrict__ Bbase, long sB, int ldb, int K,
    float* __restrict__ Cf, long sC, int ldc,
    f16* __restrict__ C16, const f16* __restrict__ GU, long sGU)
{
  __shared__ f16 As[128 * 64];
  __shared__ f16 Bs[128 * 64];
  const int b = blockIdx.z;
  const int tid = threadIdx.x, lane = tid & 63, wave = tid >> 6;
  const int wm = wave >> 1, wn = wave & 1;
  const int quad = lane >> 4, l15 = lane & 15;
  const f16* Ap = Abase + (size_t)b * sA + (size_t)(blockIdx.x * 128) * lda;
  const f16* Bp = Bbase + (size_t)b * sB + (size_t)(blockIdx.y * 128) * ldb;

  float4v acc[4][4];
#pragma unroll
  for (int i = 0; i < 4; ++i)
#pragma unroll
    for (int j = 0; j < 4; ++j)
#pragma unroll
      for (int r = 0; r < 4; ++r) acc[i][j][r] = 0.f;

  for (int kt = 0; kt < K; kt += 64) {
    __syncthreads();
#pragma unroll
    for (int q = 0; q < 4; ++q) {
      int pos = q * 256 + wave * 64 + lane;
      int m = pos >> 3, jc = pos & 7;
      int g = jc ^ (m & 7);
      gload_lds16(Ap + (size_t)m * lda + kt + g * 8,
                  As + (q * 256 + wave * 64) * 8);
      gload_lds16(Bp + (size_t)m * ldb + kt + g * 8,
                  Bs + (q * 256 + wave * 64) * 8);
    }
    __syncthreads();
#pragma unroll
    for (int ks = 0; ks < 2; ++ks) {
      half8 af[4], bf[4];
      int kc = ks * 4 + quad;
#pragma unroll
      for (int i = 0; i < 4; ++i) {
        int m = wm * 64 + i * 16 + l15;
        af[i] = *(const half8*)(As + m * 64 + ((kc ^ (m & 7)) * 8));
        int n = wn * 64 + i * 16 + l15;
        bf[i] = *(const half8*)(Bs + n * 64 + ((kc ^ (n & 7)) * 8));
      }
#pragma unroll
      for (int i = 0; i < 4; ++i)
#pragma unroll
        for (int j = 0; j < 4; ++j)
          acc[i][j] = __builtin_amdgcn_mfma_f32_16x16x32_f16(af[i], bf[j],
                                                             acc[i][j], 0, 0, 0);
    }
  }

#pragma unroll
  for (int i = 0; i < 4; ++i) {
#pragma unroll
    for (int j = 0; j < 4; ++j) {
      int m0 = blockIdx.x * 128 + wm * 64 + i * 16 + quad * 4;
      int n = blockIdx.y * 128 + wn * 64 + j * 16 + l15;
#pragma unroll
      for (int r = 0; r < 4; ++r) {
        int m = m0 + r;
        if constexpr (EPI == 0) {
          Cf[(size_t)b * sC + (size_t)m * ldc + n] = acc[i][j][r];
        } else {
          float v = acc[i][j][r] - (float)GU[(size_t)b * sGU + (size_t)m * 256 + n];
          C16[(size_t)b * sC + (size_t)m * ldc + n] = (f16)v;
        }
      }
    }
  }
}

// ----------------------------------------------------------------------------
// S3: per-batch Cholesky + blocked triangular inversion -> Linv fp16.
// grid (128), 1024 threads.
//
// Redesigned phase 1 (was 663 us, 8.5e7 LDS bank-conflict cycles, 256 block
// barriers):
//   - Pan stride padded 32 -> 33 (kills the 32-way same-bank pattern).
//   - 32x32 pivot block factored in wave-0 REGISTERS via __shfl column
//     broadcasts (right-looking, fully unrolled: no LDS, no block barriers).
//   - Below-pivot rows: one thread per row, fully-unrolled forward solve
//     against pivot L in LDS (all reads same-address broadcasts).
//   - 4 barriers per panel instead of ~34.
// Trailing rank-32 update / diag-block inversion / X-panel phases kept.
// ----------------------------------------------------------------------------
__global__ __launch_bounds__(1024) void chol_kernel(float* __restrict__ Sg,
                                                    f16* __restrict__ Linv)
{
  __shared__ float Pan[256 * 33];   // chol panel (stride 33) / X-panel (stride 32)
  __shared__ float Dinv[8 * 528];   // 8 diag-block inverses, packed lower
  __shared__ float Tscr[32 * 32];
  __shared__ float rdg[32];         // reciprocal pivot diagonals
  const int b = blockIdx.x, tid = threadIdx.x;
  float* Lg = Sg + (size_t)b * 65536;
  f16* Lo = Linv + (size_t)b * 65536;

  // zero-init Linv (upper triangle must read as 0 in K4)
  for (int t = tid; t < 16384; t += 1024) ((uint64_t*)Lo)[t] = 0ull;

  // ---- Phase 1: blocked right-looking Cholesky, in place on Lg ----
  for (int p = 0; p < 8; ++p) {
    const int c0 = p * 32, rows = 256 - c0;
    __syncthreads();
    // load panel (coalesced global, conflict-free LDS: stride 33)
    for (int t = tid; t < rows * 32; t += 1024) {
      int r = t >> 5, k = t & 31;
      Pan[r * 33 + k] = Lg[(size_t)(c0 + r) * 256 + c0 + k];
    }
    __syncthreads();

    // (a) 32x32 pivot block: wave 0, row per lane, registers + shfl
    if (tid < 64) {
      const int i = tid & 31;
      float a[32];
#pragma unroll
      for (int k = 0; k < 32; ++k) a[k] = Pan[i * 33 + k];
#pragma unroll
      for (int jj = 0; jj < 32; ++jj) {
        float pv = __shfl(a[jj], jj);
        float d = sqrtf(fmaxf(pv, 1e-20f));
        float rd = 1.f / d;
        float lij = (i == jj) ? d : a[jj] * rd;
        a[jj] = lij;
        if (tid == jj) rdg[jj] = rd;
#pragma unroll
        for (int k = jj + 1; k < 32; ++k) {
          float ckj = __shfl(lij, k);   // L[k][jj] from lane k
          a[k] -= lij * ckj;            // rank-1 update (upper junk unused)
        }
      }
      if (tid < 32) {
#pragma unroll
        for (int k = 0; k < 32; ++k)
          if (k <= i) Pan[i * 33 + k] = a[k];
      }
    }
    __syncthreads();

    // (b) below-pivot rows: forward triangular solve, one row per thread
    const int nbr = rows - 32;
    if (tid < nbr) {
      const int r = 32 + tid;
      float v[32];
#pragma unroll
      for (int k = 0; k < 32; ++k) v[k] = Pan[r * 33 + k];
#pragma unroll
      for (int jj = 0; jj < 32; ++jj) {
        float x = v[jj] * rdg[jj];
        v[jj] = x;
#pragma unroll
        for (int k = jj + 1; k < 32; ++k)
          v[k] -= x * Pan[k * 33 + jj];  // broadcast read of pivot L
      }
#pragma unroll
      for (int k = 0; k < 32; ++k) Pan[r * 33 + k] = v[k];
    }
    __syncthreads();

    // write panel back (disjoint from trailing region -> no barrier needed)
    for (int t = tid; t < rows * 32; t += 1024) {
      int r = t >> 5, k = t & 31;
      Lg[(size_t)(c0 + r) * 256 + c0 + k] = Pan[r * 33 + k];
    }
    // (c) trailing rank-32 update on global (8x8 register blocks)
    int R = 256 - (c0 + 32);
    if (R > 0) {
      int nb = R >> 3, nblk = nb * (nb + 1) / 2;
      for (int bx = tid; bx < nblk; bx += 1024) {
        int br = (int)((sqrtf(8.f * bx + 1.f) - 1.f) * 0.5f);
        while ((br + 1) * (br + 2) / 2 <= bx) ++br;
        while (br * (br + 1) / 2 > bx) --br;
        int bc = bx - br * (br + 1) / 2;
        int il = 32 + br * 8, jl = 32 + bc * 8;
        float acc[8][8];
#pragma unroll
        for (int r = 0; r < 8; ++r) {
          const float* cp = Lg + (size_t)(c0 + il + r) * 256 + c0 + jl;
#pragma unroll
          for (int c = 0; c < 8; ++c) acc[r][c] = cp[c];
        }
        for (int k = 0; k < 32; ++k) {
          float a2[8], bb[8];
#pragma unroll
          for (int r = 0; r < 8; ++r) a2[r] = Pan[(il + r) * 33 + k];
#pragma unroll
          for (int c = 0; c < 8; ++c) bb[c] = Pan[(jl + c) * 33 + k];
#pragma unroll
          for (int r = 0; r < 8; ++r)
#pragma unroll
            for (int c = 0; c < 8; ++c) acc[r][c] -= a2[r] * bb[c];
        }
#pragma unroll
        for (int r = 0; r < 8; ++r) {
          float* cp = Lg + (size_t)(c0 + il + r) * 256 + c0 + jl;
#pragma unroll
          for (int c = 0; c < 8; ++c) cp[c] = acc[r][c];
        }
      }
    }
  }
  __syncthreads();

  // ---- Phase 2: invert the 8 diagonal 32x32 blocks (256 threads) ----
  if (tid < 256) {
    int w = tid >> 5, c = tid & 31;
    const float* Lb = Lg + (size_t)(32 * w) * 256 + 32 * w;
    for (int i = c; i < 32; ++i) {
      float s = (i == c) ? 1.f : 0.f;
      for (int k = c; k < i; ++k)
        s -= Lb[i * 256 + k] * Dinv[w * 528 + k * (k + 1) / 2 + c];
      Dinv[w * 528 + i * (i + 1) / 2 + c] = s / Lb[i * 256 + i];
    }
  }
  __syncthreads();

  // ---- Phase 3: X = L^-1 by column panels of 32, X-panel in LDS ----
  for (int p = 0; p < 8; ++p) {
    {
      int i = tid >> 5, k = tid & 31;
      float val = (k <= i) ? Dinv[p * 528 + i * (i + 1) / 2 + k] : 0.f;
      Pan[i * 32 + k] = val;
      Lo[(size_t)(32 * p + i) * 256 + 32 * p + k] = (f16)val;
    }
    __syncthreads();
    for (int r = p + 1; r < 8; ++r) {
      int i = tid >> 5, j = tid & 31;
      float s = 0.f;
      for (int a = p; a < r; ++a) {
        const float* Lrow = Lg + (size_t)(32 * r + i) * 256 + 32 * a;
        const float* Xp = Pan + ((a - p) * 32) * 32 + j;
        for (int kk = 0; kk < 32; ++kk) s += Lrow[kk] * Xp[kk * 32];
      }
      Tscr[i * 32 + j] = s;
      __syncthreads();
      float val = 0.f;
      for (int kk = 0; kk <= i; ++kk)
        val -= Dinv[r * 528 + i * (i + 1) / 2 + kk] * Tscr[kk * 32 + j];
      Pan[((r - p) * 32 + i) * 32 + j] = val;
      Lo[(size_t)(32 * r + i) * 256 + 32 * p + j] = (f16)val;
      __syncthreads();
    }
  }
}

// ----------------------------------------------------------------------------
extern "C" void kernel_launch(void* const* d_in, const int* in_sizes, int n_in,
                              void* d_out, int out_size, void* d_ws,
                              size_t ws_size, hipStream_t stream) {
  const float* M = (const float*)d_in[0];
  const float* G = (const float*)d_in[1];
  const float* U = (const float*)d_in[2];
  const float* lr = (const float*)d_in[3];
  const float* sl = (const float*)d_in[4];
  float* out = (float*)d_out;

  const size_t big = (size_t)128 * 2304 * 256;  // elements per big tensor
  char* ws = (char*)d_ws;
  size_t off = 0;
  auto alloc = [&](size_t bytes) -> char* {
    char* p = ws + off;
    off += (bytes + 255) & ~(size_t)255;
    return p;
  };
  f16* M16 = (f16*)alloc(big * 2);
  f16* Mt  = (f16*)alloc(big * 2);   // reused as B16 after K1
  f16* Gt  = (f16*)alloc(big * 2);   // reused as Bt after K1
  f16* GU  = (f16*)alloc(big * 2);
  f16* W   = (f16*)alloc((size_t)128 * 65536 * 2);  // reused as Linv after K2
  float* AR = (float*)alloc((size_t)128 * 65536 * 4);  // A raw, reused as S/L

  f16* B16 = Mt;
  f16* Bt = Gt;
  float* S = AR;
  f16* LINV = W;

  dim3 blk(256);
  // prep: M16/Mt/Gt/GU
  prep_kernel<<<dim3(36, 2, 128), blk, 0, stream>>>(M, G, U, lr, sl, M16, Mt,
                                                    Gt, GU);
  // K1: A = Mt * Gt^T = M^T G  (fp32)
  gemm_kernel<0><<<dim3(2, 2, 128), blk, 0, stream>>>(
      Mt, 589824, 2304, Gt, 589824, 2304, 2304, AR, 65536, 256, nullptr,
      nullptr, 0);
  // K1b: W = I + 0.5c (A + A^T)
  symw_kernel<<<dim3(10, 1, 128), blk, 0, stream>>>(AR, lr, sl, W);
  // K2: B = M16 * W^T - GU  (W symmetric), fp16 out
  gemm_kernel<1><<<dim3(18, 2, 128), blk, 0, stream>>>(
      M16, 589824, 256, W, 65536, 256, 256, nullptr, 589824, 256, B16, GU,
      589824);
  // T: Bt = B^T
  tranb_kernel<<<dim3(36, 1, 128), blk, 0, stream>>>(B16, Bt);
  // K3: S = Bt * Bt^T = B^T B (fp32)
  gemm_kernel<0><<<dim3(2, 2, 128), blk, 0, stream>>>(
      Bt, 589824, 2304, Bt, 589824, 2304, 2304, S, 65536, 256, nullptr,
      nullptr, 0);
  // S3: chol + triangular inverse -> LINV fp16
  chol_kernel<<<dim3(128), dim3(1024), 0, stream>>>(S, LINV);
  // K4: out = LINV * B16^T = L^-1 B^T  (fp32, [256][2304] per batch)
  gemm_kernel<0><<<dim3(2, 18, 128), blk, 0, stream>>>(
      LINV, 65536, 256, B16, 589824, 256, 256, out, 589824, 2304, nullptr,
      nullptr, 0);
}